// Round 10
// baseline (200.262 us; speedup 1.0000x reference)
//
#include <hip/hip_runtime.h>
#include <math.h>

// GenSP: SSN superpixels, x(1,64,384,384), stoken=16.
// S=576 superpixels (24x24 grid of 16x16 px blocks), C=64, P=147456, N_ITER=3.
// f64 label chain (R1/R3/R4/R6 bit-matched np f64 ref, absmax 0.0).
// R9 = R6 (proven 136us) + global_load_lds DMA staging of the 16KB x-chunk:
// 16 x dwordx4 direct-to-LDS (1KB/instr, zero VGPR dests) -> distance phase
// reads LDS instead of latency-stalled global b32. Dot phase keeps R6's
// L2-hot float4 global re-read. All numerics bit-identical to R6.

#define NC   64
#define IMW  384
#define HWP  (384*384)
#define NSH  24
#define NSW  24
#define NS   (NSH*NSW)
#define NBG  (NS*4)       // 2304 chunk-blocks (4 x 64px per superpixel block)

typedef const __attribute__((address_space(1))) void* gas1_t;
typedef __attribute__((address_space(3))) void* las3_t;

// ---- K1a: per-chunk partial sums for initial centroids (validated R4) -----
__global__ __launch_bounds__(256) void k_cent_part(const float* __restrict__ x,
                                                   double* __restrict__ centp) {
    int bg = blockIdx.x, b = bg >> 2, g = bg & 3;
    int by = b / NSW, bx = b % NSW;
    int t = threadIdx.x, q = t >> 2, r = t & 3;
    const float* gp = x + (size_t)q * HWP + (size_t)(by * 16 + g * 4) * IMW + bx * 16 + r * 4;
    double s = 0.0;
    #pragma unroll
    for (int j = 0; j < 4; ++j) {
        float4 v = *(const float4*)(gp + (size_t)j * IMW);
        s += (double)v.x; s += (double)v.y; s += (double)v.z; s += (double)v.w;
    }
    s += __shfl_xor(s, 1, 64);
    s += __shfl_xor(s, 2, 64);
    if (r == 0) centp[(size_t)bg * NC + q] = s;
}

// ---- K1b: reduce 4 chunk partials -> initial cent + cnorm -----------------
__global__ __launch_bounds__(64) void k_cent_red(const double* __restrict__ centp,
                                                 double* __restrict__ cent,
                                                 double* __restrict__ cnorm) {
    int s = blockIdx.x, c = threadIdx.x;
    double v = centp[(size_t)(s * 4 + 0) * NC + c] + centp[(size_t)(s * 4 + 1) * NC + c]
             + centp[(size_t)(s * 4 + 2) * NC + c] + centp[(size_t)(s * 4 + 3) * NC + c];
    v *= (1.0 / 256.0);
    cent[s * NC + c] = v;
    double n2 = v * v;
    #pragma unroll
    for (int off = 32; off >= 1; off >>= 1) n2 += __shfl_down(n2, off, 64);
    if (c == 0) cnorm[s] = n2;
}

// stage 64px x 64ch chunk into LDS c-major [c][p] via direct-to-LDS DMA:
// call i covers channels 4i..4i+3; lane l -> channel 4i+(l>>4),
// pixel quad (l&15): row (l&15)>>2, cols ((l&15)&3)*4 .. +3.
__device__ __forceinline__ void dma_chunk(const float* __restrict__ x,
        float* __restrict__ xb, int by, int bx, int g, int t) {
    int sub = t & 15, cofs = t >> 4;
    const float* gsrc = x + (size_t)cofs * HWP
        + (size_t)(by * 16 + g * 4 + (sub >> 2)) * IMW + bx * 16 + (sub & 3) * 4;
    #pragma unroll
    for (int i = 0; i < 16; ++i) {
        __builtin_amdgcn_global_load_lds((gas1_t)(gsrc + (size_t)(4 * i) * HWP),
                                         (las3_t)&xb[i * 256], 16, 0, 0);
    }
}

// ---- K2: soft iteration ---------------------------------------------------
__global__ __launch_bounds__(64) void k_iter(const float* __restrict__ x,
        const double* __restrict__ cent, const double* __restrict__ cnorm,
        double* __restrict__ bnum, double* __restrict__ bden) {
    int bg = blockIdx.x, b = bg >> 2, g = bg & 3;
    int by = b / NSW, bx = b % NSW;
    int t = threadIdx.x;
    __shared__ float  xb[64 * 64];       // 16 KB, c-major [c][p]
    __shared__ double aff[9][66];        // 4.75 KB

    dma_chunk(x, xb, by, bx, g, t);      // issue DMA first (16KB in flight)

    int cand[9]; bool vld[9];
    #pragma unroll
    for (int k = 0; k < 9; ++k) {        // pure blockIdx math -> SGPR
        int cy = by + k / 3 - 1, cx = bx + k % 3 - 1;
        vld[k] = (cy >= 0) && (cy < NSH) && (cx >= 0) && (cx < NSW);
        cand[k] = vld[k] ? (cy * NSW + cx) : 0;
    }
    asm volatile("s_waitcnt vmcnt(0)" ::: "memory");
    __syncthreads();

    // distance: thread = pixel; x from LDS, cent via s_load (uniform c)
    int p = t;
    double dot[9] = {0, 0, 0, 0, 0, 0, 0, 0, 0};
    #pragma unroll 4
    for (int c = 0; c < NC; ++c) {
        double xv = (double)xb[c * 64 + p];
        #pragma unroll
        for (int k = 0; k < 9; ++k)
            dot[k] = fma(xv, cent[(size_t)cand[k] * NC + c], dot[k]);
    }
    double d[9], m = -1e300;
    #pragma unroll
    for (int k = 0; k < 9; ++k) {
        d[k] = fma(dot[k], -2.0, cnorm[cand[k]]);
        if (vld[k]) m = fmax(m, -d[k]);
    }
    double e[9], ss = 0.0;
    #pragma unroll
    for (int k = 0; k < 9; ++k) { e[k] = vld[k] ? exp(-d[k] - m) : 0.0; ss += e[k]; }
    double inv = 1.0 / ss;
    #pragma unroll
    for (int k = 0; k < 9; ++k) { e[k] *= inv; aff[k][t] = e[k]; }

    #pragma unroll
    for (int k = 0; k < 9; ++k) {        // den per (chunk,k), R6 reduce order
        double dn = e[k];
        #pragma unroll
        for (int off = 32; off >= 1; off >>= 1) dn += __shfl_down(dn, off, 64);
        if (t == 0) bden[(size_t)bg * 9 + k] = dn;
    }
    __syncthreads();

    // dot phase: lane = channel; x re-read as float4 (L2-hot), aff broadcast
    int c = t;
    double acc[9] = {0, 0, 0, 0, 0, 0, 0, 0, 0};
    const float* xq = x + (size_t)c * HWP + (size_t)(by * 16 + g * 4) * IMW + bx * 16;
    for (int r = 0; r < 4; ++r) {
        #pragma unroll
        for (int q = 0; q < 4; ++q) {
            float4 xv = *(const float4*)(xq + (size_t)r * IMW + q * 4);
            int pp = r * 16 + q * 4;
            #pragma unroll
            for (int k = 0; k < 9; ++k) {
                acc[k] = fma(aff[k][pp + 0], (double)xv.x, acc[k]);
                acc[k] = fma(aff[k][pp + 1], (double)xv.y, acc[k]);
                acc[k] = fma(aff[k][pp + 2], (double)xv.z, acc[k]);
                acc[k] = fma(aff[k][pp + 3], (double)xv.w, acc[k]);
            }
        }
    }
    #pragma unroll
    for (int k = 0; k < 9; ++k) bnum[((size_t)bg * 9 + k) * NC + c] = acc[k];
}

// ---- K3: centroid update: gather 9k x 4g partials -> cent + cnorm ---------
__global__ __launch_bounds__(64) void k_gather_cent(const double* __restrict__ bnum,
                                                    const double* __restrict__ bden,
                                                    double* __restrict__ cent,
                                                    double* __restrict__ cnorm) {
    int s = blockIdx.x, c = threadIdx.x;
    int sy = s / NSW, sx = s % NSW;
    double num = 0.0, den = 0.0;
    #pragma unroll
    for (int k = 0; k < 9; ++k) {
        int by2 = sy - (k / 3 - 1), bx2 = sx - (k % 3 - 1);
        if (by2 >= 0 && by2 < NSH && bx2 >= 0 && bx2 < NSW) {
            int b2 = by2 * NSW + bx2;
            #pragma unroll
            for (int g = 0; g < 4; ++g) {
                int bg = b2 * 4 + g;
                num += bnum[((size_t)bg * 9 + k) * NC + c];
                den += bden[(size_t)bg * 9 + k];
            }
        }
    }
    double v = num / (den + 1e-16);
    cent[s * NC + c] = v;
    double n2 = v * v;
    #pragma unroll
    for (int off = 32; off >= 1; off >>= 1) n2 += __shfl_down(n2, off, 64);
    if (c == 0) cnorm[s] = n2;
}

// ---- K4: final: argmin labels + hard-label (indicator) partial sums -------
__global__ __launch_bounds__(64) void k_final(const float* __restrict__ x,
        const double* __restrict__ cent, const double* __restrict__ cnorm,
        int* __restrict__ labels,
        double* __restrict__ bnum, double* __restrict__ bden) {
    int bg = blockIdx.x, b = bg >> 2, g = bg & 3;
    int by = b / NSW, bx = b % NSW;
    int t = threadIdx.x;
    __shared__ float  xb[64 * 64];
    __shared__ double aff[9][66];

    dma_chunk(x, xb, by, bx, g, t);

    int cand[9]; bool vld[9];
    #pragma unroll
    for (int k = 0; k < 9; ++k) {
        int cy = by + k / 3 - 1, cx = bx + k % 3 - 1;
        vld[k] = (cy >= 0) && (cy < NSH) && (cx >= 0) && (cx < NSW);
        cand[k] = vld[k] ? (cy * NSW + cx) : 0;
    }
    asm volatile("s_waitcnt vmcnt(0)" ::: "memory");
    __syncthreads();

    int p = t;
    double dot[9] = {0, 0, 0, 0, 0, 0, 0, 0, 0};
    #pragma unroll 4
    for (int c = 0; c < NC; ++c) {
        double xv = (double)xb[c * 64 + p];
        #pragma unroll
        for (int k = 0; k < 9; ++k)
            dot[k] = fma(xv, cent[(size_t)cand[k] * NC + c], dot[k]);
    }
    double bestd = 1e300; int bk = 0;
    #pragma unroll
    for (int k = 0; k < 9; ++k) {
        double dv = fma(dot[k], -2.0, cnorm[cand[k]]);
        if (vld[k] && dv < bestd) { bestd = dv; bk = k; }   // first-wins
    }
    labels[(size_t)(by * 16 + g * 4 + (t >> 4)) * IMW + bx * 16 + (t & 15)] =
        (by + bk / 3 - 1) * NSW + (bx + bk % 3 - 1);
    #pragma unroll
    for (int k = 0; k < 9; ++k) aff[k][t] = (bk == k) ? 1.0 : 0.0;

    #pragma unroll
    for (int k = 0; k < 9; ++k) {        // counts per (chunk,k)
        int cnt = (bk == k);
        #pragma unroll
        for (int off = 32; off >= 1; off >>= 1) cnt += __shfl_down(cnt, off, 64);
        if (t == 0) bden[(size_t)bg * 9 + k] = (double)cnt;
    }
    __syncthreads();

    int c = t;
    double acc[9] = {0, 0, 0, 0, 0, 0, 0, 0, 0};
    const float* xq = x + (size_t)c * HWP + (size_t)(by * 16 + g * 4) * IMW + bx * 16;
    for (int r = 0; r < 4; ++r) {
        #pragma unroll
        for (int q = 0; q < 4; ++q) {
            float4 xv = *(const float4*)(xq + (size_t)r * IMW + q * 4);
            int pp = r * 16 + q * 4;
            #pragma unroll
            for (int k = 0; k < 9; ++k) {
                acc[k] = fma(aff[k][pp + 0], (double)xv.x, acc[k]);
                acc[k] = fma(aff[k][pp + 1], (double)xv.y, acc[k]);
                acc[k] = fma(aff[k][pp + 2], (double)xv.z, acc[k]);
                acc[k] = fma(aff[k][pp + 3], (double)xv.w, acc[k]);
            }
        }
    }
    #pragma unroll
    for (int k = 0; k < 9; ++k) bnum[((size_t)bg * 9 + k) * NC + c] = acc[k];
}

// ---- K5: gather paint sums -> per-superpixel channel means (f32) ----------
__global__ __launch_bounds__(64) void k_means_(const double* __restrict__ bnum,
                                               const double* __restrict__ bden,
                                               float* __restrict__ means) {
    int s = blockIdx.x, c = threadIdx.x;
    int sy = s / NSW, sx = s % NSW;
    double num = 0.0, den = 0.0;
    #pragma unroll
    for (int k = 0; k < 9; ++k) {
        int by2 = sy - (k / 3 - 1), bx2 = sx - (k % 3 - 1);
        if (by2 >= 0 && by2 < NSH && bx2 >= 0 && bx2 < NSW) {
            int b2 = by2 * NSW + bx2;
            #pragma unroll
            for (int g = 0; g < 4; ++g) {
                int bg = b2 * 4 + g;
                num += bnum[((size_t)bg * 9 + k) * NC + c];
                den += bden[(size_t)bg * 9 + k];
            }
        }
    }
    means[s * NC + c] = (float)(num / fmax(den, 1.0));
}

// ---- K6: paint out[c][p] = means[lab[p]][c]; 4 px x 4 ch per thread -------
__global__ __launch_bounds__(256) void k_paint(const int* __restrict__ labels,
                                               const float* __restrict__ means,
                                               float* __restrict__ out) {
    int p0 = (blockIdx.x * 256 + threadIdx.x) * 4;
    int4 lb = *(const int4*)&labels[p0];
    int c0 = blockIdx.y * 4;
    #pragma unroll
    for (int j = 0; j < 4; ++j) {
        int c = c0 + j;
        float4 o;
        o.x = means[lb.x * NC + c];
        o.y = means[lb.y * NC + c];
        o.z = means[lb.z * NC + c];
        o.w = means[lb.w * NC + c];
        *(float4*)&out[(size_t)c * HWP + p0] = o;
    }
}

extern "C" void kernel_launch(void* const* d_in, const int* in_sizes, int n_in,
                              void* d_out, int out_size, void* d_ws, size_t ws_size,
                              hipStream_t stream) {
    const float* x = (const float*)d_in[0];
    float* out = (float*)d_out;
    char* ws = (char*)d_ws;
    char* od = (char*)d_out;

    constexpr size_t CENTP_B = (size_t)NBG * NC * 8;      // 1179648
    constexpr size_t CENT_B  = (size_t)NS * NC * 8;       // 294912 (x2)
    constexpr size_t CNRM_B  = (size_t)NS * 8;            // 4608   (x2)
    constexpr size_t BNUM_B  = (size_t)NBG * 9 * NC * 8;  // 10616832
    constexpr size_t BDEN_B  = (size_t)NBG * 9 * 8;       // 165888
    constexpr size_t LAB_B   = (size_t)HWP * 4;           // 589824
    constexpr size_t MEANS_B = (size_t)NS * NC * 4;       // 147456
    constexpr size_t T_PAINT = LAB_B + MEANS_B;           // must live in ws
    constexpr size_t T_CENT  = T_PAINT + 2 * (CENT_B + CNRM_B);
    constexpr size_t T_ALL   = T_CENT + CENTP_B + BNUM_B + BDEN_B;

    int* labels = (int*)ws;
    float* means = (float*)(ws + LAB_B);
    double *centA, *centB, *cnormA, *cnormB, *centp, *bnum, *bden;
    if (ws_size >= T_ALL) {
        centA  = (double*)(ws + T_PAINT);
        centB  = (double*)(ws + T_PAINT + CENT_B);
        cnormA = (double*)(ws + T_PAINT + 2 * CENT_B);
        cnormB = (double*)(ws + T_PAINT + 2 * CENT_B + CNRM_B);
        centp  = (double*)(ws + T_CENT);
        bnum   = (double*)(ws + T_CENT + CENTP_B);
        bden   = (double*)(ws + T_CENT + CENTP_B + BNUM_B);
    } else if (ws_size >= T_CENT) {
        centA  = (double*)(ws + T_PAINT);
        centB  = (double*)(ws + T_PAINT + CENT_B);
        cnormA = (double*)(ws + T_PAINT + 2 * CENT_B);
        cnormB = (double*)(ws + T_PAINT + 2 * CENT_B + CNRM_B);
        centp  = (double*)od;
        bnum   = (double*)(od + CENTP_B);
        bden   = (double*)(od + CENTP_B + BNUM_B);
    } else {
        centp  = (double*)od;
        bnum   = (double*)(od + CENTP_B);
        bden   = (double*)(od + CENTP_B + BNUM_B);
        centA  = (double*)(od + CENTP_B + BNUM_B + BDEN_B);
        centB  = (double*)(od + CENTP_B + BNUM_B + BDEN_B + CENT_B);
        cnormA = (double*)(od + CENTP_B + BNUM_B + BDEN_B + 2 * CENT_B);
        cnormB = (double*)(od + CENTP_B + BNUM_B + BDEN_B + 2 * CENT_B + CNRM_B);
    }
    // all d_out-resident scratch is consumed before k_paint overwrites d_out

    k_cent_part<<<NBG, 256, 0, stream>>>(x, centp);
    k_cent_red<<<NS, 64, 0, stream>>>(centp, centA, cnormA);
    k_iter<<<NBG, 64, 0, stream>>>(x, centA, cnormA, bnum, bden);
    k_gather_cent<<<NS, 64, 0, stream>>>(bnum, bden, centB, cnormB);
    k_iter<<<NBG, 64, 0, stream>>>(x, centB, cnormB, bnum, bden);
    k_gather_cent<<<NS, 64, 0, stream>>>(bnum, bden, centA, cnormA);
    k_final<<<NBG, 64, 0, stream>>>(x, centA, cnormA, labels, bnum, bden);
    k_means_<<<NS, 64, 0, stream>>>(bnum, bden, means);
    k_paint<<<dim3(HWP / 1024, NC / 4), 256, 0, stream>>>(labels, means, out);
}

// Round 11
// 154.636 us; speedup vs baseline: 1.2951x; 1.2951x over previous
//
#include <hip/hip_runtime.h>
#include <math.h>

// GenSP: SSN superpixels, x(1,64,384,384), stoken=16.
// S=576 superpixels (24x24 grid of 16x16 px blocks), C=64, P=147456, N_ITER=3.
// f64 label chain (R1/R3/R4/R6 bit-matched np f64 ref, absmax 0.0).
// R11 = R6 (proven 136us) + ONE change: distance phase issues all 64 x-loads
// into a register array BEFORE the fma loop (MLP 4 -> 64 loads in flight,
// one latency wait instead of 16 unroll-4 group waits). Bit-identical math.

#define NC   64
#define IMW  384
#define HWP  (384*384)
#define NSH  24
#define NSW  24
#define NS   (NSH*NSW)
#define NBG  (NS*4)       // 2304 chunk-blocks (4 x 64px per superpixel block)

// ---- K1a: per-chunk partial sums for initial centroids (validated R4) -----
__global__ __launch_bounds__(256) void k_cent_part(const float* __restrict__ x,
                                                   double* __restrict__ centp) {
    int bg = blockIdx.x, b = bg >> 2, g = bg & 3;
    int by = b / NSW, bx = b % NSW;
    int t = threadIdx.x, q = t >> 2, r = t & 3;
    const float* gp = x + (size_t)q * HWP + (size_t)(by * 16 + g * 4) * IMW + bx * 16 + r * 4;
    double s = 0.0;
    #pragma unroll
    for (int j = 0; j < 4; ++j) {
        float4 v = *(const float4*)(gp + (size_t)j * IMW);
        s += (double)v.x; s += (double)v.y; s += (double)v.z; s += (double)v.w;
    }
    s += __shfl_xor(s, 1, 64);
    s += __shfl_xor(s, 2, 64);
    if (r == 0) centp[(size_t)bg * NC + q] = s;
}

// ---- K1b: reduce 4 chunk partials -> initial cent + cnorm -----------------
__global__ __launch_bounds__(64) void k_cent_red(const double* __restrict__ centp,
                                                 double* __restrict__ cent,
                                                 double* __restrict__ cnorm) {
    int s = blockIdx.x, c = threadIdx.x;
    double v = centp[(size_t)(s * 4 + 0) * NC + c] + centp[(size_t)(s * 4 + 1) * NC + c]
             + centp[(size_t)(s * 4 + 2) * NC + c] + centp[(size_t)(s * 4 + 3) * NC + c];
    v *= (1.0 / 256.0);
    cent[s * NC + c] = v;
    double n2 = v * v;
    #pragma unroll
    for (int off = 32; off >= 1; off >>= 1) n2 += __shfl_down(n2, off, 64);
    if (c == 0) cnorm[s] = n2;
}

// ---- K2: soft iteration: dist(scalar-pipe cent) + softmax + dot -----------
__global__ __launch_bounds__(64) void k_iter(const float* __restrict__ x,
        const double* __restrict__ cent, const double* __restrict__ cnorm,
        double* __restrict__ bnum, double* __restrict__ bden) {
    int bg = blockIdx.x, b = bg >> 2, g = bg & 3;
    int by = b / NSW, bx = b % NSW;
    int t = threadIdx.x;
    __shared__ double aff[9][66];        // [k][pixel], 4.75 KB

    int cand[9]; bool vld[9];
    #pragma unroll
    for (int k = 0; k < 9; ++k) {        // pure blockIdx math -> SGPR
        int cy = by + k / 3 - 1, cx = bx + k % 3 - 1;
        vld[k] = (cy >= 0) && (cy < NSH) && (cx >= 0) && (cx < NSW);
        cand[k] = vld[k] ? (cy * NSW + cx) : 0;
    }

    // distance: thread = pixel. R11: batch ALL 64 loads first (64-deep MLP),
    // then the fma loop runs against registers; cent via s_load (uniform).
    const float* xp = x + (size_t)(by * 16 + g * 4 + (t >> 4)) * IMW + bx * 16 + (t & 15);
    float xv[NC];
    #pragma unroll
    for (int c = 0; c < NC; ++c) xv[c] = xp[(size_t)c * HWP];

    double dot[9] = {0, 0, 0, 0, 0, 0, 0, 0, 0};
    #pragma unroll
    for (int c = 0; c < NC; ++c) {
        double xd = (double)xv[c];
        #pragma unroll
        for (int k = 0; k < 9; ++k)
            dot[k] = fma(xd, cent[(size_t)cand[k] * NC + c], dot[k]);
    }
    double d[9], m = -1e300;
    #pragma unroll
    for (int k = 0; k < 9; ++k) {
        d[k] = fma(dot[k], -2.0, cnorm[cand[k]]);
        if (vld[k]) m = fmax(m, -d[k]);
    }
    double e[9], ss = 0.0;
    #pragma unroll
    for (int k = 0; k < 9; ++k) { e[k] = vld[k] ? exp(-d[k] - m) : 0.0; ss += e[k]; }
    double inv = 1.0 / ss;
    #pragma unroll
    for (int k = 0; k < 9; ++k) { e[k] *= inv; aff[k][t] = e[k]; }

    #pragma unroll
    for (int k = 0; k < 9; ++k) {        // den per (chunk,k), R6 reduce order
        double dn = e[k];
        #pragma unroll
        for (int off = 32; off >= 1; off >>= 1) dn += __shfl_down(dn, off, 64);
        if (t == 0) bden[(size_t)bg * 9 + k] = dn;
    }
    __syncthreads();

    // dot phase: lane = channel; x re-read as float4 (L2-hot), aff broadcast
    int c = t;
    double acc[9] = {0, 0, 0, 0, 0, 0, 0, 0, 0};
    const float* xq = x + (size_t)c * HWP + (size_t)(by * 16 + g * 4) * IMW + bx * 16;
    for (int r = 0; r < 4; ++r) {
        #pragma unroll
        for (int q = 0; q < 4; ++q) {
            float4 xw = *(const float4*)(xq + (size_t)r * IMW + q * 4);
            int pp = r * 16 + q * 4;
            #pragma unroll
            for (int k = 0; k < 9; ++k) {
                acc[k] = fma(aff[k][pp + 0], (double)xw.x, acc[k]);
                acc[k] = fma(aff[k][pp + 1], (double)xw.y, acc[k]);
                acc[k] = fma(aff[k][pp + 2], (double)xw.z, acc[k]);
                acc[k] = fma(aff[k][pp + 3], (double)xw.w, acc[k]);
            }
        }
    }
    #pragma unroll
    for (int k = 0; k < 9; ++k) bnum[((size_t)bg * 9 + k) * NC + c] = acc[k];
}

// ---- K3: centroid update: gather 9k x 4g partials -> cent + cnorm ---------
__global__ __launch_bounds__(64) void k_gather_cent(const double* __restrict__ bnum,
                                                    const double* __restrict__ bden,
                                                    double* __restrict__ cent,
                                                    double* __restrict__ cnorm) {
    int s = blockIdx.x, c = threadIdx.x;
    int sy = s / NSW, sx = s % NSW;
    double num = 0.0, den = 0.0;
    #pragma unroll
    for (int k = 0; k < 9; ++k) {
        int by2 = sy - (k / 3 - 1), bx2 = sx - (k % 3 - 1);
        if (by2 >= 0 && by2 < NSH && bx2 >= 0 && bx2 < NSW) {
            int b2 = by2 * NSW + bx2;
            #pragma unroll
            for (int g = 0; g < 4; ++g) {
                int bg = b2 * 4 + g;
                num += bnum[((size_t)bg * 9 + k) * NC + c];
                den += bden[(size_t)bg * 9 + k];
            }
        }
    }
    double v = num / (den + 1e-16);
    cent[s * NC + c] = v;
    double n2 = v * v;
    #pragma unroll
    for (int off = 32; off >= 1; off >>= 1) n2 += __shfl_down(n2, off, 64);
    if (c == 0) cnorm[s] = n2;
}

// ---- K4: final: argmin labels + hard-label (indicator) partial sums -------
__global__ __launch_bounds__(64) void k_final(const float* __restrict__ x,
        const double* __restrict__ cent, const double* __restrict__ cnorm,
        int* __restrict__ labels,
        double* __restrict__ bnum, double* __restrict__ bden) {
    int bg = blockIdx.x, b = bg >> 2, g = bg & 3;
    int by = b / NSW, bx = b % NSW;
    int t = threadIdx.x;
    __shared__ double aff[9][66];

    int cand[9]; bool vld[9];
    #pragma unroll
    for (int k = 0; k < 9; ++k) {
        int cy = by + k / 3 - 1, cx = bx + k % 3 - 1;
        vld[k] = (cy >= 0) && (cy < NSH) && (cx >= 0) && (cx < NSW);
        cand[k] = vld[k] ? (cy * NSW + cx) : 0;
    }

    const float* xp = x + (size_t)(by * 16 + g * 4 + (t >> 4)) * IMW + bx * 16 + (t & 15);
    float xv[NC];
    #pragma unroll
    for (int c = 0; c < NC; ++c) xv[c] = xp[(size_t)c * HWP];

    double dot[9] = {0, 0, 0, 0, 0, 0, 0, 0, 0};
    #pragma unroll
    for (int c = 0; c < NC; ++c) {
        double xd = (double)xv[c];
        #pragma unroll
        for (int k = 0; k < 9; ++k)
            dot[k] = fma(xd, cent[(size_t)cand[k] * NC + c], dot[k]);
    }
    double bestd = 1e300; int bk = 0;
    #pragma unroll
    for (int k = 0; k < 9; ++k) {
        double dv = fma(dot[k], -2.0, cnorm[cand[k]]);
        if (vld[k] && dv < bestd) { bestd = dv; bk = k; }   // first-wins
    }
    labels[(size_t)(by * 16 + g * 4 + (t >> 4)) * IMW + bx * 16 + (t & 15)] =
        (by + bk / 3 - 1) * NSW + (bx + bk % 3 - 1);
    #pragma unroll
    for (int k = 0; k < 9; ++k) aff[k][t] = (bk == k) ? 1.0 : 0.0;

    #pragma unroll
    for (int k = 0; k < 9; ++k) {        // counts per (chunk,k)
        int cnt = (bk == k);
        #pragma unroll
        for (int off = 32; off >= 1; off >>= 1) cnt += __shfl_down(cnt, off, 64);
        if (t == 0) bden[(size_t)bg * 9 + k] = (double)cnt;
    }
    __syncthreads();

    int c = t;
    double acc[9] = {0, 0, 0, 0, 0, 0, 0, 0, 0};
    const float* xq = x + (size_t)c * HWP + (size_t)(by * 16 + g * 4) * IMW + bx * 16;
    for (int r = 0; r < 4; ++r) {
        #pragma unroll
        for (int q = 0; q < 4; ++q) {
            float4 xw = *(const float4*)(xq + (size_t)r * IMW + q * 4);
            int pp = r * 16 + q * 4;
            #pragma unroll
            for (int k = 0; k < 9; ++k) {
                acc[k] = fma(aff[k][pp + 0], (double)xw.x, acc[k]);
                acc[k] = fma(aff[k][pp + 1], (double)xw.y, acc[k]);
                acc[k] = fma(aff[k][pp + 2], (double)xw.z, acc[k]);
                acc[k] = fma(aff[k][pp + 3], (double)xw.w, acc[k]);
            }
        }
    }
    #pragma unroll
    for (int k = 0; k < 9; ++k) bnum[((size_t)bg * 9 + k) * NC + c] = acc[k];
}

// ---- K5: gather paint sums -> per-superpixel channel means (f32) ----------
__global__ __launch_bounds__(64) void k_means_(const double* __restrict__ bnum,
                                               const double* __restrict__ bden,
                                               float* __restrict__ means) {
    int s = blockIdx.x, c = threadIdx.x;
    int sy = s / NSW, sx = s % NSW;
    double num = 0.0, den = 0.0;
    #pragma unroll
    for (int k = 0; k < 9; ++k) {
        int by2 = sy - (k / 3 - 1), bx2 = sx - (k % 3 - 1);
        if (by2 >= 0 && by2 < NSH && bx2 >= 0 && bx2 < NSW) {
            int b2 = by2 * NSW + bx2;
            #pragma unroll
            for (int g = 0; g < 4; ++g) {
                int bg = b2 * 4 + g;
                num += bnum[((size_t)bg * 9 + k) * NC + c];
                den += bden[(size_t)bg * 9 + k];
            }
        }
    }
    means[s * NC + c] = (float)(num / fmax(den, 1.0));
}

// ---- K6: paint out[c][p] = means[lab[p]][c]; 4 px x 4 ch per thread -------
__global__ __launch_bounds__(256) void k_paint(const int* __restrict__ labels,
                                               const float* __restrict__ means,
                                               float* __restrict__ out) {
    int p0 = (blockIdx.x * 256 + threadIdx.x) * 4;
    int4 lb = *(const int4*)&labels[p0];
    int c0 = blockIdx.y * 4;
    #pragma unroll
    for (int j = 0; j < 4; ++j) {
        int c = c0 + j;
        float4 o;
        o.x = means[lb.x * NC + c];
        o.y = means[lb.y * NC + c];
        o.z = means[lb.z * NC + c];
        o.w = means[lb.w * NC + c];
        *(float4*)&out[(size_t)c * HWP + p0] = o;
    }
}

extern "C" void kernel_launch(void* const* d_in, const int* in_sizes, int n_in,
                              void* d_out, int out_size, void* d_ws, size_t ws_size,
                              hipStream_t stream) {
    const float* x = (const float*)d_in[0];
    float* out = (float*)d_out;
    char* ws = (char*)d_ws;
    char* od = (char*)d_out;

    constexpr size_t CENTP_B = (size_t)NBG * NC * 8;      // 1179648
    constexpr size_t CENT_B  = (size_t)NS * NC * 8;       // 294912 (x2)
    constexpr size_t CNRM_B  = (size_t)NS * 8;            // 4608   (x2)
    constexpr size_t BNUM_B  = (size_t)NBG * 9 * NC * 8;  // 10616832
    constexpr size_t BDEN_B  = (size_t)NBG * 9 * 8;       // 165888
    constexpr size_t LAB_B   = (size_t)HWP * 4;           // 589824
    constexpr size_t MEANS_B = (size_t)NS * NC * 4;       // 147456
    constexpr size_t T_PAINT = LAB_B + MEANS_B;           // must live in ws
    constexpr size_t T_CENT  = T_PAINT + 2 * (CENT_B + CNRM_B);
    constexpr size_t T_ALL   = T_CENT + CENTP_B + BNUM_B + BDEN_B;

    int* labels = (int*)ws;
    float* means = (float*)(ws + LAB_B);
    double *centA, *centB, *cnormA, *cnormB, *centp, *bnum, *bden;
    if (ws_size >= T_ALL) {
        centA  = (double*)(ws + T_PAINT);
        centB  = (double*)(ws + T_PAINT + CENT_B);
        cnormA = (double*)(ws + T_PAINT + 2 * CENT_B);
        cnormB = (double*)(ws + T_PAINT + 2 * CENT_B + CNRM_B);
        centp  = (double*)(ws + T_CENT);
        bnum   = (double*)(ws + T_CENT + CENTP_B);
        bden   = (double*)(ws + T_CENT + CENTP_B + BNUM_B);
    } else if (ws_size >= T_CENT) {
        centA  = (double*)(ws + T_PAINT);
        centB  = (double*)(ws + T_PAINT + CENT_B);
        cnormA = (double*)(ws + T_PAINT + 2 * CENT_B);
        cnormB = (double*)(ws + T_PAINT + 2 * CENT_B + CNRM_B);
        centp  = (double*)od;
        bnum   = (double*)(od + CENTP_B);
        bden   = (double*)(od + CENTP_B + BNUM_B);
    } else {
        centp  = (double*)od;
        bnum   = (double*)(od + CENTP_B);
        bden   = (double*)(od + CENTP_B + BNUM_B);
        centA  = (double*)(od + CENTP_B + BNUM_B + BDEN_B);
        centB  = (double*)(od + CENTP_B + BNUM_B + BDEN_B + CENT_B);
        cnormA = (double*)(od + CENTP_B + BNUM_B + BDEN_B + 2 * CENT_B);
        cnormB = (double*)(od + CENTP_B + BNUM_B + BDEN_B + 2 * CENT_B + CNRM_B);
    }
    // all d_out-resident scratch is consumed before k_paint overwrites d_out

    k_cent_part<<<NBG, 256, 0, stream>>>(x, centp);
    k_cent_red<<<NS, 64, 0, stream>>>(centp, centA, cnormA);
    k_iter<<<NBG, 64, 0, stream>>>(x, centA, cnormA, bnum, bden);
    k_gather_cent<<<NS, 64, 0, stream>>>(bnum, bden, centB, cnormB);
    k_iter<<<NBG, 64, 0, stream>>>(x, centB, cnormB, bnum, bden);
    k_gather_cent<<<NS, 64, 0, stream>>>(bnum, bden, centA, cnormA);
    k_final<<<NBG, 64, 0, stream>>>(x, centA, cnormA, labels, bnum, bden);
    k_means_<<<NS, 64, 0, stream>>>(bnum, bden, means);
    k_paint<<<dim3(HWP / 1024, NC / 4), 256, 0, stream>>>(labels, means, out);
}

// Round 12
// 130.115 us; speedup vs baseline: 1.5391x; 1.1885x over previous
//
#include <hip/hip_runtime.h>
#include <math.h>

// GenSP: SSN superpixels, x(1,64,384,384), stoken=16.
// S=576 superpixels (24x24 grid of 16x16 px blocks), C=64, P=147456, N_ITER=3.
// f64 label chain (R1/R3/R4/R6 bit-matched np f64 ref, absmax 0.0).
// R12 = R6 (proven 136us) + ONE change: the 9 candidate centroid rows are
// staged into LDS at block start (9 coalesced 512B loads, one wait) and the
// distance loop reads them as wave-uniform LDS broadcasts -- eliminating the
// 576 per-thread s_load K$-miss waits that dominated the distance phase.
// Bit-identical math to R6.

#define NC   64
#define IMW  384
#define HWP  (384*384)
#define NSH  24
#define NSW  24
#define NS   (NSH*NSW)
#define NBG  (NS*4)       // 2304 chunk-blocks (4 x 64px per superpixel block)

// ---- K1a: per-chunk partial sums for initial centroids (validated R4) -----
__global__ __launch_bounds__(256) void k_cent_part(const float* __restrict__ x,
                                                   double* __restrict__ centp) {
    int bg = blockIdx.x, b = bg >> 2, g = bg & 3;
    int by = b / NSW, bx = b % NSW;
    int t = threadIdx.x, q = t >> 2, r = t & 3;
    const float* gp = x + (size_t)q * HWP + (size_t)(by * 16 + g * 4) * IMW + bx * 16 + r * 4;
    double s = 0.0;
    #pragma unroll
    for (int j = 0; j < 4; ++j) {
        float4 v = *(const float4*)(gp + (size_t)j * IMW);
        s += (double)v.x; s += (double)v.y; s += (double)v.z; s += (double)v.w;
    }
    s += __shfl_xor(s, 1, 64);
    s += __shfl_xor(s, 2, 64);
    if (r == 0) centp[(size_t)bg * NC + q] = s;
}

// ---- K1b: reduce 4 chunk partials -> initial cent + cnorm -----------------
__global__ __launch_bounds__(64) void k_cent_red(const double* __restrict__ centp,
                                                 double* __restrict__ cent,
                                                 double* __restrict__ cnorm) {
    int s = blockIdx.x, c = threadIdx.x;
    double v = centp[(size_t)(s * 4 + 0) * NC + c] + centp[(size_t)(s * 4 + 1) * NC + c]
             + centp[(size_t)(s * 4 + 2) * NC + c] + centp[(size_t)(s * 4 + 3) * NC + c];
    v *= (1.0 / 256.0);
    cent[s * NC + c] = v;
    double n2 = v * v;
    #pragma unroll
    for (int off = 32; off >= 1; off >>= 1) n2 += __shfl_down(n2, off, 64);
    if (c == 0) cnorm[s] = n2;
}

// ---- K2: soft iteration: dist(LDS-staged cent) + softmax + dot ------------
__global__ __launch_bounds__(64) void k_iter(const float* __restrict__ x,
        const double* __restrict__ cent, const double* __restrict__ cnorm,
        double* __restrict__ bnum, double* __restrict__ bden) {
    int bg = blockIdx.x, b = bg >> 2, g = bg & 3;
    int by = b / NSW, bx = b % NSW;
    int t = threadIdx.x;
    __shared__ double scent[9][64];      // 4.6 KB staged candidate centroids
    __shared__ double aff[9][66];        // 4.75 KB

    int cand[9]; bool vld[9];
    #pragma unroll
    for (int k = 0; k < 9; ++k) {        // pure blockIdx math -> SGPR
        int cy = by + k / 3 - 1, cx = bx + k % 3 - 1;
        vld[k] = (cy >= 0) && (cy < NSH) && (cx >= 0) && (cx < NSW);
        cand[k] = vld[k] ? (cy * NSW + cx) : 0;
    }

    // stage: 9 coalesced 512B row loads, all in flight, one wait
    #pragma unroll
    for (int j = 0; j < 9; ++j)
        scent[j][t] = cent[(size_t)cand[j] * NC + t];
    __syncthreads();

    // distance: thread = pixel; x global (R6 pattern), cent via LDS broadcast
    const float* xp = x + (size_t)(by * 16 + g * 4 + (t >> 4)) * IMW + bx * 16 + (t & 15);
    double dot[9] = {0, 0, 0, 0, 0, 0, 0, 0, 0};
    #pragma unroll 4
    for (int c = 0; c < NC; ++c) {
        double xv = (double)xp[(size_t)c * HWP];
        #pragma unroll
        for (int k = 0; k < 9; ++k)
            dot[k] = fma(xv, scent[k][c], dot[k]);
    }
    double d[9], m = -1e300;
    #pragma unroll
    for (int k = 0; k < 9; ++k) {
        d[k] = fma(dot[k], -2.0, cnorm[cand[k]]);
        if (vld[k]) m = fmax(m, -d[k]);
    }
    double e[9], ss = 0.0;
    #pragma unroll
    for (int k = 0; k < 9; ++k) { e[k] = vld[k] ? exp(-d[k] - m) : 0.0; ss += e[k]; }
    double inv = 1.0 / ss;
    #pragma unroll
    for (int k = 0; k < 9; ++k) { e[k] *= inv; aff[k][t] = e[k]; }

    #pragma unroll
    for (int k = 0; k < 9; ++k) {        // den per (chunk,k), R6 reduce order
        double dn = e[k];
        #pragma unroll
        for (int off = 32; off >= 1; off >>= 1) dn += __shfl_down(dn, off, 64);
        if (t == 0) bden[(size_t)bg * 9 + k] = dn;
    }
    __syncthreads();

    // dot phase: lane = channel; x re-read as float4 (L2-hot), aff broadcast
    int c = t;
    double acc[9] = {0, 0, 0, 0, 0, 0, 0, 0, 0};
    const float* xq = x + (size_t)c * HWP + (size_t)(by * 16 + g * 4) * IMW + bx * 16;
    for (int r = 0; r < 4; ++r) {
        #pragma unroll
        for (int q = 0; q < 4; ++q) {
            float4 xw = *(const float4*)(xq + (size_t)r * IMW + q * 4);
            int pp = r * 16 + q * 4;
            #pragma unroll
            for (int k = 0; k < 9; ++k) {
                acc[k] = fma(aff[k][pp + 0], (double)xw.x, acc[k]);
                acc[k] = fma(aff[k][pp + 1], (double)xw.y, acc[k]);
                acc[k] = fma(aff[k][pp + 2], (double)xw.z, acc[k]);
                acc[k] = fma(aff[k][pp + 3], (double)xw.w, acc[k]);
            }
        }
    }
    #pragma unroll
    for (int k = 0; k < 9; ++k) bnum[((size_t)bg * 9 + k) * NC + c] = acc[k];
}

// ---- K3: centroid update: gather 9k x 4g partials -> cent + cnorm ---------
__global__ __launch_bounds__(64) void k_gather_cent(const double* __restrict__ bnum,
                                                    const double* __restrict__ bden,
                                                    double* __restrict__ cent,
                                                    double* __restrict__ cnorm) {
    int s = blockIdx.x, c = threadIdx.x;
    int sy = s / NSW, sx = s % NSW;
    double num = 0.0, den = 0.0;
    #pragma unroll
    for (int k = 0; k < 9; ++k) {
        int by2 = sy - (k / 3 - 1), bx2 = sx - (k % 3 - 1);
        if (by2 >= 0 && by2 < NSH && bx2 >= 0 && bx2 < NSW) {
            int b2 = by2 * NSW + bx2;
            #pragma unroll
            for (int g = 0; g < 4; ++g) {
                int bg = b2 * 4 + g;
                num += bnum[((size_t)bg * 9 + k) * NC + c];
                den += bden[(size_t)bg * 9 + k];
            }
        }
    }
    double v = num / (den + 1e-16);
    cent[s * NC + c] = v;
    double n2 = v * v;
    #pragma unroll
    for (int off = 32; off >= 1; off >>= 1) n2 += __shfl_down(n2, off, 64);
    if (c == 0) cnorm[s] = n2;
}

// ---- K4: final: argmin labels + hard-label (indicator) partial sums -------
__global__ __launch_bounds__(64) void k_final(const float* __restrict__ x,
        const double* __restrict__ cent, const double* __restrict__ cnorm,
        int* __restrict__ labels,
        double* __restrict__ bnum, double* __restrict__ bden) {
    int bg = blockIdx.x, b = bg >> 2, g = bg & 3;
    int by = b / NSW, bx = b % NSW;
    int t = threadIdx.x;
    __shared__ double scent[9][64];
    __shared__ double aff[9][66];

    int cand[9]; bool vld[9];
    #pragma unroll
    for (int k = 0; k < 9; ++k) {
        int cy = by + k / 3 - 1, cx = bx + k % 3 - 1;
        vld[k] = (cy >= 0) && (cy < NSH) && (cx >= 0) && (cx < NSW);
        cand[k] = vld[k] ? (cy * NSW + cx) : 0;
    }

    #pragma unroll
    for (int j = 0; j < 9; ++j)
        scent[j][t] = cent[(size_t)cand[j] * NC + t];
    __syncthreads();

    const float* xp = x + (size_t)(by * 16 + g * 4 + (t >> 4)) * IMW + bx * 16 + (t & 15);
    double dot[9] = {0, 0, 0, 0, 0, 0, 0, 0, 0};
    #pragma unroll 4
    for (int c = 0; c < NC; ++c) {
        double xv = (double)xp[(size_t)c * HWP];
        #pragma unroll
        for (int k = 0; k < 9; ++k)
            dot[k] = fma(xv, scent[k][c], dot[k]);
    }
    double bestd = 1e300; int bk = 0;
    #pragma unroll
    for (int k = 0; k < 9; ++k) {
        double dv = fma(dot[k], -2.0, cnorm[cand[k]]);
        if (vld[k] && dv < bestd) { bestd = dv; bk = k; }   // first-wins
    }
    labels[(size_t)(by * 16 + g * 4 + (t >> 4)) * IMW + bx * 16 + (t & 15)] =
        (by + bk / 3 - 1) * NSW + (bx + bk % 3 - 1);
    #pragma unroll
    for (int k = 0; k < 9; ++k) aff[k][t] = (bk == k) ? 1.0 : 0.0;

    #pragma unroll
    for (int k = 0; k < 9; ++k) {        // counts per (chunk,k)
        int cnt = (bk == k);
        #pragma unroll
        for (int off = 32; off >= 1; off >>= 1) cnt += __shfl_down(cnt, off, 64);
        if (t == 0) bden[(size_t)bg * 9 + k] = (double)cnt;
    }
    __syncthreads();

    int c = t;
    double acc[9] = {0, 0, 0, 0, 0, 0, 0, 0, 0};
    const float* xq = x + (size_t)c * HWP + (size_t)(by * 16 + g * 4) * IMW + bx * 16;
    for (int r = 0; r < 4; ++r) {
        #pragma unroll
        for (int q = 0; q < 4; ++q) {
            float4 xw = *(const float4*)(xq + (size_t)r * IMW + q * 4);
            int pp = r * 16 + q * 4;
            #pragma unroll
            for (int k = 0; k < 9; ++k) {
                acc[k] = fma(aff[k][pp + 0], (double)xw.x, acc[k]);
                acc[k] = fma(aff[k][pp + 1], (double)xw.y, acc[k]);
                acc[k] = fma(aff[k][pp + 2], (double)xw.z, acc[k]);
                acc[k] = fma(aff[k][pp + 3], (double)xw.w, acc[k]);
            }
        }
    }
    #pragma unroll
    for (int k = 0; k < 9; ++k) bnum[((size_t)bg * 9 + k) * NC + c] = acc[k];
}

// ---- K5: gather paint sums -> per-superpixel channel means (f32) ----------
__global__ __launch_bounds__(64) void k_means_(const double* __restrict__ bnum,
                                               const double* __restrict__ bden,
                                               float* __restrict__ means) {
    int s = blockIdx.x, c = threadIdx.x;
    int sy = s / NSW, sx = s % NSW;
    double num = 0.0, den = 0.0;
    #pragma unroll
    for (int k = 0; k < 9; ++k) {
        int by2 = sy - (k / 3 - 1), bx2 = sx - (k % 3 - 1);
        if (by2 >= 0 && by2 < NSH && bx2 >= 0 && bx2 < NSW) {
            int b2 = by2 * NSW + bx2;
            #pragma unroll
            for (int g = 0; g < 4; ++g) {
                int bg = b2 * 4 + g;
                num += bnum[((size_t)bg * 9 + k) * NC + c];
                den += bden[(size_t)bg * 9 + k];
            }
        }
    }
    means[s * NC + c] = (float)(num / fmax(den, 1.0));
}

// ---- K6: paint out[c][p] = means[lab[p]][c]; 4 px x 4 ch per thread -------
__global__ __launch_bounds__(256) void k_paint(const int* __restrict__ labels,
                                               const float* __restrict__ means,
                                               float* __restrict__ out) {
    int p0 = (blockIdx.x * 256 + threadIdx.x) * 4;
    int4 lb = *(const int4*)&labels[p0];
    int c0 = blockIdx.y * 4;
    #pragma unroll
    for (int j = 0; j < 4; ++j) {
        int c = c0 + j;
        float4 o;
        o.x = means[lb.x * NC + c];
        o.y = means[lb.y * NC + c];
        o.z = means[lb.z * NC + c];
        o.w = means[lb.w * NC + c];
        *(float4*)&out[(size_t)c * HWP + p0] = o;
    }
}

extern "C" void kernel_launch(void* const* d_in, const int* in_sizes, int n_in,
                              void* d_out, int out_size, void* d_ws, size_t ws_size,
                              hipStream_t stream) {
    const float* x = (const float*)d_in[0];
    float* out = (float*)d_out;
    char* ws = (char*)d_ws;
    char* od = (char*)d_out;

    constexpr size_t CENTP_B = (size_t)NBG * NC * 8;      // 1179648
    constexpr size_t CENT_B  = (size_t)NS * NC * 8;       // 294912 (x2)
    constexpr size_t CNRM_B  = (size_t)NS * 8;            // 4608   (x2)
    constexpr size_t BNUM_B  = (size_t)NBG * 9 * NC * 8;  // 10616832
    constexpr size_t BDEN_B  = (size_t)NBG * 9 * 8;       // 165888
    constexpr size_t LAB_B   = (size_t)HWP * 4;           // 589824
    constexpr size_t MEANS_B = (size_t)NS * NC * 4;       // 147456
    constexpr size_t T_PAINT = LAB_B + MEANS_B;           // must live in ws
    constexpr size_t T_CENT  = T_PAINT + 2 * (CENT_B + CNRM_B);
    constexpr size_t T_ALL   = T_CENT + CENTP_B + BNUM_B + BDEN_B;

    int* labels = (int*)ws;
    float* means = (float*)(ws + LAB_B);
    double *centA, *centB, *cnormA, *cnormB, *centp, *bnum, *bden;
    if (ws_size >= T_ALL) {
        centA  = (double*)(ws + T_PAINT);
        centB  = (double*)(ws + T_PAINT + CENT_B);
        cnormA = (double*)(ws + T_PAINT + 2 * CENT_B);
        cnormB = (double*)(ws + T_PAINT + 2 * CENT_B + CNRM_B);
        centp  = (double*)(ws + T_CENT);
        bnum   = (double*)(ws + T_CENT + CENTP_B);
        bden   = (double*)(ws + T_CENT + CENTP_B + BNUM_B);
    } else if (ws_size >= T_CENT) {
        centA  = (double*)(ws + T_PAINT);
        centB  = (double*)(ws + T_PAINT + CENT_B);
        cnormA = (double*)(ws + T_PAINT + 2 * CENT_B);
        cnormB = (double*)(ws + T_PAINT + 2 * CENT_B + CNRM_B);
        centp  = (double*)od;
        bnum   = (double*)(od + CENTP_B);
        bden   = (double*)(od + CENTP_B + BNUM_B);
    } else {
        centp  = (double*)od;
        bnum   = (double*)(od + CENTP_B);
        bden   = (double*)(od + CENTP_B + BNUM_B);
        centA  = (double*)(od + CENTP_B + BNUM_B + BDEN_B);
        centB  = (double*)(od + CENTP_B + BNUM_B + BDEN_B + CENT_B);
        cnormA = (double*)(od + CENTP_B + BNUM_B + BDEN_B + 2 * CENT_B);
        cnormB = (double*)(od + CENTP_B + BNUM_B + BDEN_B + 2 * CENT_B + CNRM_B);
    }
    // all d_out-resident scratch is consumed before k_paint overwrites d_out

    k_cent_part<<<NBG, 256, 0, stream>>>(x, centp);
    k_cent_red<<<NS, 64, 0, stream>>>(centp, centA, cnormA);
    k_iter<<<NBG, 64, 0, stream>>>(x, centA, cnormA, bnum, bden);
    k_gather_cent<<<NS, 64, 0, stream>>>(bnum, bden, centB, cnormB);
    k_iter<<<NBG, 64, 0, stream>>>(x, centB, cnormB, bnum, bden);
    k_gather_cent<<<NS, 64, 0, stream>>>(bnum, bden, centA, cnormA);
    k_final<<<NBG, 64, 0, stream>>>(x, centA, cnormA, labels, bnum, bden);
    k_means_<<<NS, 64, 0, stream>>>(bnum, bden, means);
    k_paint<<<dim3(HWP / 1024, NC / 4), 256, 0, stream>>>(labels, means, out);
}

// Round 13
// 122.385 us; speedup vs baseline: 1.6363x; 1.0632x over previous
//
#include <hip/hip_runtime.h>
#include <math.h>

// GenSP: SSN superpixels, x(1,64,384,384), stoken=16.
// S=576 superpixels (24x24 grid of 16x16 px blocks), C=64, P=147456, N_ITER=3.
// f64 label chain (R1/R3/R4/R6/R12 bit-matched np f64 ref, absmax 0.0).
// R13 = R12 structure + finer chunks: 32px per 64-thread block (2 threads/px,
// channel-halves combined via shfl_xor(32)), grid 2304->4608 => 4.5 waves/SIMD
// (was 2.25) to hide x-load latency. Waves stay fully independent (R8's
// cross-wave combine machinery was the regression cause, not the wave count).

#define NC   64
#define IMW  384
#define HWP  (384*384)
#define NSH  24
#define NSW  24
#define NS   (NSH*NSW)
#define NCP  (NS*4)       // cent_init partial chunks (4 x 64px), unchanged
#define NBG  (NS*8)       // 4608 iter chunks (8 x 32px per superpixel block)

// ---- K1a: per-chunk partial sums for initial centroids (validated R4) -----
__global__ __launch_bounds__(256) void k_cent_part(const float* __restrict__ x,
                                                   double* __restrict__ centp) {
    int bg = blockIdx.x, b = bg >> 2, g = bg & 3;
    int by = b / NSW, bx = b % NSW;
    int t = threadIdx.x, q = t >> 2, r = t & 3;
    const float* gp = x + (size_t)q * HWP + (size_t)(by * 16 + g * 4) * IMW + bx * 16 + r * 4;
    double s = 0.0;
    #pragma unroll
    for (int j = 0; j < 4; ++j) {
        float4 v = *(const float4*)(gp + (size_t)j * IMW);
        s += (double)v.x; s += (double)v.y; s += (double)v.z; s += (double)v.w;
    }
    s += __shfl_xor(s, 1, 64);
    s += __shfl_xor(s, 2, 64);
    if (r == 0) centp[(size_t)bg * NC + q] = s;
}

// ---- K1b: reduce 4 chunk partials -> initial cent + cnorm -----------------
__global__ __launch_bounds__(64) void k_cent_red(const double* __restrict__ centp,
                                                 double* __restrict__ cent,
                                                 double* __restrict__ cnorm) {
    int s = blockIdx.x, c = threadIdx.x;
    double v = centp[(size_t)(s * 4 + 0) * NC + c] + centp[(size_t)(s * 4 + 1) * NC + c]
             + centp[(size_t)(s * 4 + 2) * NC + c] + centp[(size_t)(s * 4 + 3) * NC + c];
    v *= (1.0 / 256.0);
    cent[s * NC + c] = v;
    double n2 = v * v;
    #pragma unroll
    for (int off = 32; off >= 1; off >>= 1) n2 += __shfl_down(n2, off, 64);
    if (c == 0) cnorm[s] = n2;
}

// ---- K2: soft iteration: 32px chunk, 2 threads/px -------------------------
__global__ __launch_bounds__(64) void k_iter(const float* __restrict__ x,
        const double* __restrict__ cent, const double* __restrict__ cnorm,
        double* __restrict__ bnum, double* __restrict__ bden) {
    int bg = blockIdx.x, b = bg >> 3, g = bg & 7;
    int by = b / NSW, bx = b % NSW;
    int t = threadIdx.x;
    int p = t & 31, h = t >> 5;          // pixel in chunk, channel-half
    __shared__ double scent[9][64];      // 4.6 KB staged candidate centroids
    __shared__ double aff[9][33];        // 2.3 KB

    int cand[9]; bool vld[9];
    #pragma unroll
    for (int k = 0; k < 9; ++k) {        // pure blockIdx math -> SGPR
        int cy = by + k / 3 - 1, cx = bx + k % 3 - 1;
        vld[k] = (cy >= 0) && (cy < NSH) && (cx >= 0) && (cx < NSW);
        cand[k] = vld[k] ? (cy * NSW + cx) : 0;
    }

    // stage: 9 coalesced 512B row loads (R12, validated)
    #pragma unroll
    for (int j = 0; j < 9; ++j)
        scent[j][t] = cent[(size_t)cand[j] * NC + t];
    __syncthreads();

    // distance: 32 channels per thread, halves combined in-wave
    const float* xp = x + (size_t)(by * 16 + g * 2 + (p >> 4)) * IMW + bx * 16 + (p & 15);
    double dot[9] = {0, 0, 0, 0, 0, 0, 0, 0, 0};
    #pragma unroll 4
    for (int i = 0; i < 32; ++i) {
        int c = h * 32 + i;
        double xv = (double)xp[(size_t)c * HWP];
        #pragma unroll
        for (int k = 0; k < 9; ++k)
            dot[k] = fma(xv, scent[k][c], dot[k]);
    }
    #pragma unroll
    for (int k = 0; k < 9; ++k) dot[k] += __shfl_xor(dot[k], 32, 64);

    double d[9], m = -1e300;
    #pragma unroll
    for (int k = 0; k < 9; ++k) {
        d[k] = fma(dot[k], -2.0, cnorm[cand[k]]);
        if (vld[k]) m = fmax(m, -d[k]);
    }
    double e[9], ss = 0.0;
    #pragma unroll
    for (int k = 0; k < 9; ++k) { e[k] = vld[k] ? exp(-d[k] - m) : 0.0; ss += e[k]; }
    double inv = 1.0 / ss;
    #pragma unroll
    for (int k = 0; k < 9; ++k) {
        e[k] *= inv;
        if (h == 0) aff[k][p] = e[k];
    }

    #pragma unroll
    for (int k = 0; k < 9; ++k) {        // den over the 32 px (lanes 0..31)
        double dn = e[k];
        #pragma unroll
        for (int off = 16; off >= 1; off >>= 1) dn += __shfl_down(dn, off, 64);
        if (t == 0) bden[(size_t)bg * 9 + k] = dn;
    }
    __syncthreads();

    // dot phase: lane = channel; 2 rows x 4 float4 (L2-hot), aff broadcast
    int c = t;
    double acc[9] = {0, 0, 0, 0, 0, 0, 0, 0, 0};
    const float* xq = x + (size_t)c * HWP + (size_t)(by * 16 + g * 2) * IMW + bx * 16;
    #pragma unroll
    for (int r = 0; r < 2; ++r) {
        #pragma unroll
        for (int q = 0; q < 4; ++q) {
            float4 xw = *(const float4*)(xq + (size_t)r * IMW + q * 4);
            int pp = r * 16 + q * 4;
            #pragma unroll
            for (int k = 0; k < 9; ++k) {
                acc[k] = fma(aff[k][pp + 0], (double)xw.x, acc[k]);
                acc[k] = fma(aff[k][pp + 1], (double)xw.y, acc[k]);
                acc[k] = fma(aff[k][pp + 2], (double)xw.z, acc[k]);
                acc[k] = fma(aff[k][pp + 3], (double)xw.w, acc[k]);
            }
        }
    }
    #pragma unroll
    for (int k = 0; k < 9; ++k) bnum[((size_t)bg * 9 + k) * NC + c] = acc[k];
}

// ---- K3: centroid update: gather 9k x 8g partials -> cent + cnorm ---------
__global__ __launch_bounds__(64) void k_gather_cent(const double* __restrict__ bnum,
                                                    const double* __restrict__ bden,
                                                    double* __restrict__ cent,
                                                    double* __restrict__ cnorm) {
    int s = blockIdx.x, c = threadIdx.x;
    int sy = s / NSW, sx = s % NSW;
    double num = 0.0, den = 0.0;
    #pragma unroll
    for (int k = 0; k < 9; ++k) {
        int by2 = sy - (k / 3 - 1), bx2 = sx - (k % 3 - 1);
        if (by2 >= 0 && by2 < NSH && bx2 >= 0 && bx2 < NSW) {
            int b2 = by2 * NSW + bx2;
            #pragma unroll
            for (int g = 0; g < 8; ++g) {
                int bg = b2 * 8 + g;
                num += bnum[((size_t)bg * 9 + k) * NC + c];
                den += bden[(size_t)bg * 9 + k];
            }
        }
    }
    double v = num / (den + 1e-16);
    cent[s * NC + c] = v;
    double n2 = v * v;
    #pragma unroll
    for (int off = 32; off >= 1; off >>= 1) n2 += __shfl_down(n2, off, 64);
    if (c == 0) cnorm[s] = n2;
}

// ---- K4: final: argmin labels + hard-label (indicator) partial sums -------
__global__ __launch_bounds__(64) void k_final(const float* __restrict__ x,
        const double* __restrict__ cent, const double* __restrict__ cnorm,
        int* __restrict__ labels,
        double* __restrict__ bnum, double* __restrict__ bden) {
    int bg = blockIdx.x, b = bg >> 3, g = bg & 7;
    int by = b / NSW, bx = b % NSW;
    int t = threadIdx.x;
    int p = t & 31, h = t >> 5;
    __shared__ double scent[9][64];
    __shared__ double aff[9][33];

    int cand[9]; bool vld[9];
    #pragma unroll
    for (int k = 0; k < 9; ++k) {
        int cy = by + k / 3 - 1, cx = bx + k % 3 - 1;
        vld[k] = (cy >= 0) && (cy < NSH) && (cx >= 0) && (cx < NSW);
        cand[k] = vld[k] ? (cy * NSW + cx) : 0;
    }

    #pragma unroll
    for (int j = 0; j < 9; ++j)
        scent[j][t] = cent[(size_t)cand[j] * NC + t];
    __syncthreads();

    const float* xp = x + (size_t)(by * 16 + g * 2 + (p >> 4)) * IMW + bx * 16 + (p & 15);
    double dot[9] = {0, 0, 0, 0, 0, 0, 0, 0, 0};
    #pragma unroll 4
    for (int i = 0; i < 32; ++i) {
        int c = h * 32 + i;
        double xv = (double)xp[(size_t)c * HWP];
        #pragma unroll
        for (int k = 0; k < 9; ++k)
            dot[k] = fma(xv, scent[k][c], dot[k]);
    }
    #pragma unroll
    for (int k = 0; k < 9; ++k) dot[k] += __shfl_xor(dot[k], 32, 64);

    double bestd = 1e300; int bk = 0;
    #pragma unroll
    for (int k = 0; k < 9; ++k) {
        double dv = fma(dot[k], -2.0, cnorm[cand[k]]);
        if (vld[k] && dv < bestd) { bestd = dv; bk = k; }   // first-wins
    }
    if (h == 0) {
        labels[(size_t)(by * 16 + g * 2 + (p >> 4)) * IMW + bx * 16 + (p & 15)] =
            (by + bk / 3 - 1) * NSW + (bx + bk % 3 - 1);
        #pragma unroll
        for (int k = 0; k < 9; ++k) aff[k][p] = (bk == k) ? 1.0 : 0.0;
    }

    #pragma unroll
    for (int k = 0; k < 9; ++k) {        // counts over the 32 px
        int cnt = (bk == k);
        #pragma unroll
        for (int off = 16; off >= 1; off >>= 1) cnt += __shfl_down(cnt, off, 64);
        if (t == 0) bden[(size_t)bg * 9 + k] = (double)cnt;
    }
    __syncthreads();

    int c = t;
    double acc[9] = {0, 0, 0, 0, 0, 0, 0, 0, 0};
    const float* xq = x + (size_t)c * HWP + (size_t)(by * 16 + g * 2) * IMW + bx * 16;
    #pragma unroll
    for (int r = 0; r < 2; ++r) {
        #pragma unroll
        for (int q = 0; q < 4; ++q) {
            float4 xw = *(const float4*)(xq + (size_t)r * IMW + q * 4);
            int pp = r * 16 + q * 4;
            #pragma unroll
            for (int k = 0; k < 9; ++k) {
                acc[k] = fma(aff[k][pp + 0], (double)xw.x, acc[k]);
                acc[k] = fma(aff[k][pp + 1], (double)xw.y, acc[k]);
                acc[k] = fma(aff[k][pp + 2], (double)xw.z, acc[k]);
                acc[k] = fma(aff[k][pp + 3], (double)xw.w, acc[k]);
            }
        }
    }
    #pragma unroll
    for (int k = 0; k < 9; ++k) bnum[((size_t)bg * 9 + k) * NC + c] = acc[k];
}

// ---- K5: gather paint sums -> per-superpixel channel means (f32) ----------
__global__ __launch_bounds__(64) void k_means_(const double* __restrict__ bnum,
                                               const double* __restrict__ bden,
                                               float* __restrict__ means) {
    int s = blockIdx.x, c = threadIdx.x;
    int sy = s / NSW, sx = s % NSW;
    double num = 0.0, den = 0.0;
    #pragma unroll
    for (int k = 0; k < 9; ++k) {
        int by2 = sy - (k / 3 - 1), bx2 = sx - (k % 3 - 1);
        if (by2 >= 0 && by2 < NSH && bx2 >= 0 && bx2 < NSW) {
            int b2 = by2 * NSW + bx2;
            #pragma unroll
            for (int g = 0; g < 8; ++g) {
                int bg = b2 * 8 + g;
                num += bnum[((size_t)bg * 9 + k) * NC + c];
                den += bden[(size_t)bg * 9 + k];
            }
        }
    }
    means[s * NC + c] = (float)(num / fmax(den, 1.0));
}

// ---- K6: paint out[c][p] = means[lab[p]][c]; 4 px x 4 ch per thread -------
__global__ __launch_bounds__(256) void k_paint(const int* __restrict__ labels,
                                               const float* __restrict__ means,
                                               float* __restrict__ out) {
    int p0 = (blockIdx.x * 256 + threadIdx.x) * 4;
    int4 lb = *(const int4*)&labels[p0];
    int c0 = blockIdx.y * 4;
    #pragma unroll
    for (int j = 0; j < 4; ++j) {
        int c = c0 + j;
        float4 o;
        o.x = means[lb.x * NC + c];
        o.y = means[lb.y * NC + c];
        o.z = means[lb.z * NC + c];
        o.w = means[lb.w * NC + c];
        *(float4*)&out[(size_t)c * HWP + p0] = o;
    }
}

extern "C" void kernel_launch(void* const* d_in, const int* in_sizes, int n_in,
                              void* d_out, int out_size, void* d_ws, size_t ws_size,
                              hipStream_t stream) {
    const float* x = (const float*)d_in[0];
    float* out = (float*)d_out;
    char* ws = (char*)d_ws;
    char* od = (char*)d_out;

    constexpr size_t CENTP_B = (size_t)NCP * NC * 8;      // 1179648
    constexpr size_t CENT_B  = (size_t)NS * NC * 8;       // 294912 (x2)
    constexpr size_t CNRM_B  = (size_t)NS * 8;            // 4608   (x2)
    constexpr size_t BNUM_B  = (size_t)NBG * 9 * NC * 8;  // 21233664
    constexpr size_t BDEN_B  = (size_t)NBG * 9 * 8;       // 331776
    constexpr size_t LAB_B   = (size_t)HWP * 4;           // 589824
    constexpr size_t MEANS_B = (size_t)NS * NC * 4;       // 147456
    constexpr size_t T_PAINT = LAB_B + MEANS_B;           // must live in ws
    constexpr size_t T_CENT  = T_PAINT + 2 * (CENT_B + CNRM_B);
    constexpr size_t T_ALL   = T_CENT + CENTP_B + BNUM_B + BDEN_B;  // ~24 MB

    int* labels = (int*)ws;
    float* means = (float*)(ws + LAB_B);
    double *centA, *centB, *cnormA, *cnormB, *centp, *bnum, *bden;
    if (ws_size >= T_ALL) {
        centA  = (double*)(ws + T_PAINT);
        centB  = (double*)(ws + T_PAINT + CENT_B);
        cnormA = (double*)(ws + T_PAINT + 2 * CENT_B);
        cnormB = (double*)(ws + T_PAINT + 2 * CENT_B + CNRM_B);
        centp  = (double*)(ws + T_CENT);
        bnum   = (double*)(ws + T_CENT + CENTP_B);
        bden   = (double*)(ws + T_CENT + CENTP_B + BNUM_B);
    } else if (ws_size >= T_CENT) {
        centA  = (double*)(ws + T_PAINT);
        centB  = (double*)(ws + T_PAINT + CENT_B);
        cnormA = (double*)(ws + T_PAINT + 2 * CENT_B);
        cnormB = (double*)(ws + T_PAINT + 2 * CENT_B + CNRM_B);
        centp  = (double*)od;
        bnum   = (double*)(od + CENTP_B);
        bden   = (double*)(od + CENTP_B + BNUM_B);
    } else {
        centp  = (double*)od;
        bnum   = (double*)(od + CENTP_B);
        bden   = (double*)(od + CENTP_B + BNUM_B);
        centA  = (double*)(od + CENTP_B + BNUM_B + BDEN_B);
        centB  = (double*)(od + CENTP_B + BNUM_B + BDEN_B + CENT_B);
        cnormA = (double*)(od + CENTP_B + BNUM_B + BDEN_B + 2 * CENT_B);
        cnormB = (double*)(od + CENTP_B + BNUM_B + BDEN_B + 2 * CENT_B + CNRM_B);
    }
    // all d_out-resident scratch is consumed before k_paint overwrites d_out
    // (22.7 MB max in the fallback paths < 37.7 MB d_out)

    k_cent_part<<<NCP, 256, 0, stream>>>(x, centp);
    k_cent_red<<<NS, 64, 0, stream>>>(centp, centA, cnormA);
    k_iter<<<NBG, 64, 0, stream>>>(x, centA, cnormA, bnum, bden);
    k_gather_cent<<<NS, 64, 0, stream>>>(bnum, bden, centB, cnormB);
    k_iter<<<NBG, 64, 0, stream>>>(x, centB, cnormB, bnum, bden);
    k_gather_cent<<<NS, 64, 0, stream>>>(bnum, bden, centA, cnormA);
    k_final<<<NBG, 64, 0, stream>>>(x, centA, cnormA, labels, bnum, bden);
    k_means_<<<NS, 64, 0, stream>>>(bnum, bden, means);
    k_paint<<<dim3(HWP / 1024, NC / 4), 256, 0, stream>>>(labels, means, out);
}